// Round 13
// baseline (2958.566 us; speedup 1.0000x reference)
//
#include <hip/hip_runtime.h>

#define TT 256
#define BB 256
#define SW 3100.0f
#define WSTRIDE 81920  // 80 blocks * 1024 B per wave (10 stages x 8 blocks)

typedef __attribute__((ext_vector_type(4))) int i32x4;

// --- inline-asm load machinery: loads no compiler pass can sink (r9-verified) ---
#define GLOAD_(dst, vo, sb, IMM) \
  asm volatile("global_load_dwordx4 %0, %1, %2 offset:" #IMM \
               : "=v"(dst) : "v"(vo), "s"(sb))
#define GLOAD(dst, vo, sb, IMM) GLOAD_(dst, vo, sb, IMM)

#define VMWAIT_(N) \
  do { asm volatile("s_waitcnt vmcnt(" #N ")" ::: "memory"); \
       __builtin_amdgcn_sched_barrier(0); } while (0)
#define VMWAIT(N) VMWAIT_(N)

__device__ __forceinline__ const char* uniform_ptr(const void* p) {
  uint64_t u = (uint64_t)(uintptr_t)p;
  uint32_t lo = __builtin_amdgcn_readfirstlane((uint32_t)u);
  uint32_t hi = __builtin_amdgcn_readfirstlane((uint32_t)(u >> 32));
  return (const char*)(uintptr_t)(((uint64_t)hi << 32) | lo);
}

// Issue one 8-KB weight stage (8 x dwordx4 per lane) into a register buffer.
__device__ __forceinline__ void wissue(i32x4 (&b)[8], const char* sb, int vo) {
  GLOAD(b[0], vo, sb, 0);    GLOAD(b[1], vo, sb, 1024);
  GLOAD(b[2], vo, sb, 2048); GLOAD(b[3], vo, sb, 3072);
  const char* s1 = sb + 4096;
  GLOAD(b[4], vo, s1, 0);    GLOAD(b[5], vo, s1, 1024);
  GLOAD(b[6], vo, s1, 2048); GLOAD(b[7], vo, s1, 3072);
}

// sigma(x) = 1/(1+2^(-x*log2e)); tanh(x) = 2*sigma(2x)-1
__device__ __forceinline__ float fsig(float x) {
  return __builtin_amdgcn_rcpf(1.0f + __builtin_amdgcn_exp2f(-1.44269504f * x));
}
__device__ __forceinline__ float ftanh(float x) {
  float t = __builtin_amdgcn_rcpf(1.0f + __builtin_amdgcn_exp2f(-2.88539008f * x));
  return __builtin_fmaf(2.0f, t, -1.0f);
}
template <int ACT>
__device__ __forceinline__ float actf(float x) {
  if (ACT == 0) return fsig(x);
  if (ACT == 1) return fmaxf(x, 0.0f);
  if (ACT == 2) return ftanh(x);
  return x;  // identity
}

__device__ __forceinline__ i32x4 mi8(i32x4 a, i32x4 b, i32x4 c) {
  return __builtin_amdgcn_mfma_i32_16x16x64_i8(a, b, c, 0, 0, 0);
}

// [16][256] int8 plane, XOR-swizzled (verified rounds 1-9).
__device__ __forceinline__ int swz(int row, int k) { return row * 256 + (k ^ ((row & 7) << 4)); }

__device__ __forceinline__ i32x4 afrag(const char* P, int lane, int kbase) {
  int row = lane & 15;
  int k0 = kbase + ((lane >> 4) << 4);
  return *(const i32x4*)(P + swz(row, k0));
}

__device__ __forceinline__ int pack4(int a, int b, int c, int d) {
  return (a & 255) | ((b & 255) << 8) | ((c & 255) << 16) | ((d & 255) << 24);
}

// state s = hi/32 + lo/4096
__device__ __forceinline__ void put_sv(char* HI, char* LO, int row, int col, float s) {
  float hf = rintf(fminf(fmaxf(s * 32.0f, -127.0f), 127.0f));
  float lf = rintf((s - hf * (1.0f / 32.0f)) * 4096.0f);
  int a = swz(row, col);
  HI[a] = (char)(int)hf;
  LO[a] = (char)(int)lf;
}

// lgkmcnt-only barrier: orders LDS, does NOT drain the vmcnt prefetch queue.
__device__ __forceinline__ void barrier_ws() {
  asm volatile("s_waitcnt lgkmcnt(0)" ::: "memory");
  __builtin_amdgcn_s_barrier();
  __builtin_amdgcn_sched_barrier(0);
}

// Genotype GEMM core: 16 cols/wave -> accs {c_hi, c_lo, h_hi, h_lo}.
__device__ __forceinline__ void gmm8(const char* SH, const char* SL, const i32x4 (&wb)[8],
                                     int lane, i32x4& ch, i32x4& cl, i32x4& hh, i32x4& hl) {
  ch = (i32x4)(0); cl = (i32x4)(0); hh = (i32x4)(0); hl = (i32x4)(0);
#pragma unroll
  for (int kt = 0; kt < 4; ++kt) {
    i32x4 Ah = afrag(SH, lane, kt * 64);
    i32x4 Al = afrag(SL, lane, kt * 64);
    ch = mi8(Ah, wb[kt * 2 + 0], ch);
    hh = mi8(Ah, wb[kt * 2 + 1], hh);
    cl = mi8(Al, wb[kt * 2 + 0], cl);
    hl = mi8(Al, wb[kt * 2 + 1], hl);
  }
}

template <int ACT, bool KEEP, bool STORE>
__device__ __forceinline__ void gepi(const i32x4& ch, const i32x4& cl, const i32x4& hh,
                                     const i32x4& hl, const float* sp, float* sn, float* ma,
                                     char* SH, char* SL, int lrow, int sc) {
  const float INVG = 1.0f / (4096.0f * SW);
#pragma unroll
  for (int j = 0; j < 4; ++j) {
    float c = (float)(ch[j] * 128 + cl[j]) * INVG;
    float h = (float)(hh[j] * 128 + hl[j]) * INVG;
    float s = __builtin_fmaf(fsig(c), actf<ACT>(h) - sp[j], sp[j]);
    ma[j] += s;
    if (KEEP) sn[j] = s;
    if (STORE) put_sv(SH, SL, lrow + j, sc, s);
  }
}

// Quantize + permute weights into per-wave (16 waves) lane-ordered block streams.
// wq[wv][stage 0..9][sb 0..7][lane][16]: sb = kt*2 + pt; pt 0 = c-cols, 1 = h-cols.
// n = pt*256 + wv*16 + (l&15); k = kt*64 + (l>>4)*16 + e.
// Stage order: W0-x, W0-h, then Ws{0,1,2,3,4,6,5,7}.
__global__ void prep(const float* __restrict__ W0, const float* __restrict__ Ws,
                     char* __restrict__ wq) {
  int gid = blockIdx.x * 256 + threadIdx.x;
  const int mi[8] = {0, 1, 2, 3, 4, 6, 5, 7};
  int wv = gid / WSTRIDE;
  int r = gid - wv * WSTRIDE;
  int blk = r >> 10, b = r & 1023;
  int l = b >> 4, e = b & 15;
  int stage = blk >> 3, sb = blk & 7;
  int kt = sb >> 1, pt = sb & 1;
  int n = pt * 256 + wv * 16 + (l & 15);
  int k = kt * 64 + ((l >> 4) << 4) + e;
  float v;
  if (stage == 0) v = W0[k * 512 + n];
  else if (stage == 1) v = W0[(256 + k) * 512 + n];
  else v = Ws[(size_t)mi[stage - 2] * 131072 + k * 512 + n];
  wq[gid] = (char)(int)rintf(v * SW);
}

__global__ __launch_bounds__(1024) void darts9(const float* __restrict__ X,
                                               const float* __restrict__ Hin,
                                               const char* __restrict__ WQ,
                                               float* __restrict__ out) {
  __shared__ char A0XH[4096], A0XL[4096], A0HH[4096], A0HL[4096];
  __shared__ char SAH[4096], SAL[4096], SBH[4096], SBL[4096], SCH[4096], SCL[4096];

  const int tid = threadIdx.x, lane = tid & 63, wv = tid >> 6;  // 16 waves
  const int ncol = lane & 15, lrow = (lane >> 4) << 2;
  const int sc = wv * 16 + ncol;  // this lane's state column
  const int rb = blockIdx.x * 16;
  const char* wsrc = uniform_ptr(WQ + (size_t)wv * WSTRIDE);
  const int wvoff = lane * 16;
  const int xvoff = ((tid >> 6) << 10) + ((tid & 63) << 4);

  float hp[4];
#pragma unroll
  for (int j = 0; j < 4; ++j) hp[j] = Hin[(rb + lrow + j) * 256 + sc];
#pragma unroll
  for (int j = 0; j < 4; ++j) put_sv(A0HH, A0HL, lrow + j, sc, hp[j]);

  // prologue queue = [x1, bA8, d4] — identical shape to steady-state [x1, bA8, st4]
  float4 xr;
  i32x4 bA[8], bB[8];
  GLOAD(xr, xvoff, uniform_ptr(X + (size_t)rb * 256), 0);
  wissue(bA, wsrc, wvoff);
  {
    i32x4 d0, d1, d2, d3;
    GLOAD(d0, wvoff, wsrc, 0); GLOAD(d1, wvoff, wsrc, 1024);
    GLOAD(d2, wvoff, wsrc, 2048); GLOAD(d3, wvoff, wsrc, 3072);
  }

  float s0[4], s1[4], s2[4], s3[4], s5[4], ma[4];
  const float INVG = 1.0f / (4096.0f * SW);

  for (int t = 0; t < TT; ++t) {
    VMWAIT(12);  // retire x (oldest); bA8 + st4/d4 stay in flight
    {  // stage x_t regs -> int8 hi/lo LDS planes (x = hi/16 + lo/2048)
      int r = tid >> 6, c0 = (tid & 63) * 4;
      float xs[4] = {xr.x, xr.y, xr.z, xr.w};
      int hb[4], lb[4];
#pragma unroll
      for (int j = 0; j < 4; ++j) {
        float hf = rintf(fminf(fmaxf(xs[j] * 16.0f, -127.0f), 127.0f));
        lb[j] = (int)rintf((xs[j] - hf * (1.0f / 16.0f)) * 2048.0f);
        hb[j] = (int)hf;
      }
      int a = swz(r, c0);
      *(int*)(A0XH + a) = pack4(hb[0], hb[1], hb[2], hb[3]);
      *(int*)(A0XL + a) = pack4(lb[0], lb[1], lb[2], lb[3]);
    }
    barrier_ws();

    // --- P0: W0 x-part (bA); issue P1 -> bB ---
    i32x4 ch, cl, hh, hl;
    wissue(bB, wsrc + 8192, wvoff);
    VMWAIT(12);  // retire bA8 (st4 + bB8 = 12 remain)
    ch = (i32x4)(0); cl = (i32x4)(0); hh = (i32x4)(0); hl = (i32x4)(0);
#pragma unroll
    for (int kt = 0; kt < 4; ++kt) {
      i32x4 Axh = afrag(A0XH, lane, kt * 64);
      i32x4 Axl = afrag(A0XL, lane, kt * 64);
      ch = mi8(Axh, bA[kt * 2 + 0], ch);
      hh = mi8(Axh, bA[kt * 2 + 1], hh);
      cl = mi8(Axl, bA[kt * 2 + 0], cl);
      hl = mi8(Axl, bA[kt * 2 + 1], hl);
    }
    // x units are 2x state units: double before adding h terms
    ch = ch + ch; cl = cl + cl; hh = hh + hh; hl = hl + hl;

    // --- P1: W0 h-part (bB); issue P2 -> bA ---
    wissue(bA, wsrc + 2 * 8192, wvoff);
    VMWAIT(8);  // retire st4 + bB8
#pragma unroll
    for (int kt = 0; kt < 4; ++kt) {
      i32x4 Ahh = afrag(A0HH, lane, kt * 64);
      i32x4 Ahl = afrag(A0HL, lane, kt * 64);
      ch = mi8(Ahh, bB[kt * 2 + 0], ch);
      hh = mi8(Ahh, bB[kt * 2 + 1], hh);
      cl = mi8(Ahl, bB[kt * 2 + 0], cl);
      hl = mi8(Ahl, bB[kt * 2 + 1], hl);
    }
#pragma unroll
    for (int j = 0; j < 4; ++j) {
      float c = (float)(ch[j] * 128 + cl[j]) * INVG;
      float h = (float)(hh[j] * 128 + hl[j]) * INVG;
      s0[j] = __builtin_fmaf(fsig(c), ftanh(h) - hp[j], hp[j]);
      put_sv(SAH, SAL, lrow + j, sc, s0[j]);
    }
    barrier_ws();

#pragma unroll
    for (int j = 0; j < 4; ++j) ma[j] = 0.0f;

    // --- P2: s1 (sigmoid, Ws0) from SA(s0) -> SB; issue P3 -> bB ---
    wissue(bB, wsrc + 3 * 8192, wvoff);
    VMWAIT(8);
    gmm8(SAH, SAL, bA, lane, ch, cl, hh, hl);
    gepi<0, true, true>(ch, cl, hh, hl, s0, s1, ma, SBH, SBL, lrow, sc);
    barrier_ws();

    // --- P3: s2 relu -> SA; issue P4 -> bA ---
    wissue(bA, wsrc + 4 * 8192, wvoff);
    VMWAIT(8);
    gmm8(SBH, SBL, bB, lane, ch, cl, hh, hl);
    gepi<1, true, true>(ch, cl, hh, hl, s1, s2, ma, SAH, SAL, lrow, sc);
    // --- P4: s3 relu -> SC; issue P5 -> bB ---
    wissue(bB, wsrc + 5 * 8192, wvoff);
    VMWAIT(8);
    gmm8(SBH, SBL, bA, lane, ch, cl, hh, hl);
    gepi<1, true, true>(ch, cl, hh, hl, s1, s3, ma, SCH, SCL, lrow, sc);
    // --- P5: s4 identity (no store); issue P6 -> bA ---
    wissue(bA, wsrc + 6 * 8192, wvoff);
    VMWAIT(8);
    gmm8(SBH, SBL, bB, lane, ch, cl, hh, hl);
    gepi<3, false, false>(ch, cl, hh, hl, s1, s1, ma, nullptr, nullptr, lrow, sc);
    barrier_ws();

    // --- P6: s5 tanh (Ws4) from SA(s2) -> SB; issue P7 -> bB ---
    wissue(bB, wsrc + 7 * 8192, wvoff);
    VMWAIT(8);
    gmm8(SAH, SAL, bA, lane, ch, cl, hh, hl);
    gepi<2, true, true>(ch, cl, hh, hl, s2, s5, ma, SBH, SBL, lrow, sc);
    // --- P7: s7 tanh (Ws6) from SC(s3), no store; issue P8 -> bA ---
    wissue(bA, wsrc + 8 * 8192, wvoff);
    VMWAIT(8);
    gmm8(SCH, SCL, bB, lane, ch, cl, hh, hl);
    gepi<2, false, false>(ch, cl, hh, hl, s3, s3, ma, nullptr, nullptr, lrow, sc);
    barrier_ws();

    // --- P8: s6 sig (Ws5) from SB(s5); issue P9 -> bB, then x(t+1) ---
    wissue(bB, wsrc + 9 * 8192, wvoff);
    {
      int tn = (t + 1 < TT) ? t + 1 : TT - 1;
      GLOAD(xr, xvoff, uniform_ptr(X + ((size_t)tn * BB + rb) * 256), 0);
    }
    VMWAIT(9);  // retire bA8 (bB8 + x1 remain)
    gmm8(SBH, SBL, bA, lane, ch, cl, hh, hl);
    gepi<0, false, false>(ch, cl, hh, hl, s5, s5, ma, nullptr, nullptr, lrow, sc);
    // --- P9: s8 relu (Ws7) from SB(s5); issue P0' -> bA ---
    wissue(bA, wsrc, wvoff);
    VMWAIT(9);  // retire bB8 (x1 + bA8 remain)
    gmm8(SBH, SBL, bB, lane, ch, cl, hh, hl);
    gepi<1, false, false>(ch, cl, hh, hl, s5, s5, ma, nullptr, nullptr, lrow, sc);

    // h = mean(states 1..8); store hiddens[t] (4 stores ride the vm queue); restage h
#pragma unroll
    for (int j = 0; j < 4; ++j) hp[j] = ma[j] * 0.125f;
#pragma unroll
    for (int j = 0; j < 4; ++j)
      out[((size_t)t * BB + rb + lrow + j) * 256 + sc] = hp[j];
    if (t == TT - 1) {
#pragma unroll
      for (int j = 0; j < 4; ++j)
        out[((size_t)TT * BB + rb + lrow + j) * 256 + sc] = hp[j];
    }
#pragma unroll
    for (int j = 0; j < 4; ++j) put_sv(A0HH, A0HL, lrow + j, sc, hp[j]);
    // loop-top barrier orders A0X/A0H LDS writes for the next W0 stage
  }
  asm volatile("s_waitcnt vmcnt(0)" ::: "memory");  // drain tail loads/stores
}

extern "C" void kernel_launch(void* const* d_in, const int* in_sizes, int n_in,
                              void* d_out, int out_size, void* d_ws, size_t ws_size,
                              hipStream_t stream) {
  (void)in_sizes; (void)n_in; (void)out_size; (void)ws_size;
  const float* X = (const float*)d_in[0];
  const float* Hin = (const float*)d_in[1];
  const float* W0 = (const float*)d_in[2];
  const float* Ws = (const float*)d_in[3];
  char* wq = (char*)d_ws;  // 16 waves * 80 KiB = 1.28 MB
  float* out = (float*)d_out;

  prep<<<5120, 256, 0, stream>>>(W0, Ws, wq);
  darts9<<<16, 1024, 0, stream>>>(X, Hin, wq, out);
}